// Round 8
// baseline (363.396 us; speedup 1.0000x reference)
//
#include <hip/hip_runtime.h>
#include <hip/hip_bf16.h>

// Attention fwd: B=4 H=16 S=2048 D=128, fp32 in/out, scale = 128^-0.5.
// Prep (rewritten for BW): one kernel, grid (16,2,64):
//   x<8 : V-transpose 256-key x 64-d tiles -> VT[bh][d][s] bf16, 512B/row writes
//   x>=8: K f32 -> bf16 streaming convert (1024 blocks, pure float4->uint2)
// fattn: UNCHANGED from round-7 verified kernel (187us, MfmaUtil 33%):
//   32x32x16 swapped operands, BM=128, dbuf LDS + ONE barrier/iter,
//   T14 named-scalar early-issue staging, defer-max, permlane32 repack.

#define SEQ 2048
#define DH  128
#define NBH 64          // B*H
#define BM  128         // Q rows per block (32 per wave)
#define BN  64          // keys per KV iteration
#define NT  (SEQ / BN)  // 32 KV tiles
#define QK_LD 136       // bf16 elems per row for K tile (128+8): 272B rows
#define VT_LD 72        // (64+8): 144B rows
#define P_LD  72        // fallback kernel only
#define PREP_LD 65      // prep V tile: [256][65] bf16 -> col reads 4-way max
#define THR 8.0f        // defer-max threshold (exp2 domain): P <= 2^8

typedef __attribute__((ext_vector_type(8))) short short8;
typedef __attribute__((ext_vector_type(4))) float f32x4;
typedef __attribute__((ext_vector_type(16))) float f32x16;
typedef __attribute__((ext_vector_type(2))) unsigned int u32x2;

#if __has_builtin(__builtin_amdgcn_exp2f)
#define EXP2F(x) __builtin_amdgcn_exp2f(x)
#else
#define EXP2F(x) exp2f(x)
#endif

// softmax scale folded with log2(e), pre-applied to Q at load time
#define CS (0.08838834764831845f * 1.44269504088896340736f)

__device__ __forceinline__ unsigned int pk_bf16(float lo, float hi) {
    union { __hip_bfloat162 h; unsigned int u; } cv;
    cv.h = __float22bfloat162_rn(make_float2(lo, hi));   // v_cvt_pk_bf16_f32
    return cv.u;
}

// Build one PV B-frag (16 keys) from 8 fp32 P values held across the lane^32
// pair. permlane32_swap exchanges the complementary dwords.
__device__ __forceinline__ short8 repack_pf(float a0, float a1, float a2, float a3,
                                            float a4, float a5, float a6, float a7,
                                            int hi) {
    unsigned pq0 = pk_bf16(a0, a1);
    unsigned pq1 = pk_bf16(a2, a3);
    unsigned pq2 = pk_bf16(a4, a5);
    unsigned pq3 = pk_bf16(a6, a7);
    union { short8 s; uint4 u; } cv;
#if __has_builtin(__builtin_amdgcn_permlane32_swap)
    u32x2 r02 = __builtin_amdgcn_permlane32_swap(pq0, pq2, false, false);
    u32x2 r13 = __builtin_amdgcn_permlane32_swap(pq1, pq3, false, false);
    cv.u.x = r02[0]; cv.u.y = r13[0]; cv.u.z = r02[1]; cv.u.w = r13[1];
    (void)hi;
#else
    unsigned px0 = (unsigned)__shfl_xor((int)pq0, 32);
    unsigned px1 = (unsigned)__shfl_xor((int)pq1, 32);
    unsigned px2 = (unsigned)__shfl_xor((int)pq2, 32);
    unsigned px3 = (unsigned)__shfl_xor((int)pq3, 32);
    cv.u.x = hi ? px2 : pq0;
    cv.u.y = hi ? px3 : pq1;
    cv.u.z = hi ? pq2 : px0;
    cv.u.w = hi ? pq3 : px1;
#endif
    return cv.s;
}

// ---- prep: x<8 -> V transpose (256-key x 64-d tile); x>=8 -> K convert ----
template<bool DOK>
__global__ __launch_bounds__(256) void prep_kernel(
        const float* __restrict__ v, unsigned short* __restrict__ vt,
        const float* __restrict__ k, unsigned short* __restrict__ kb) {
    __shared__ unsigned short tile[256 * PREP_LD];   // bf16 [key][d], 33,280 B
    const int tid = threadIdx.x;

    if (blockIdx.x >= 8) {
        // ---- K convert: 1024 blocks x 16384 floats, pure streaming ----
        if (!DOK) return;
        const int kid = (blockIdx.x - 8) + 8 * blockIdx.y + 16 * blockIdx.z;
        const float* src = k + (size_t)kid * 16384;
        unsigned short* dst = kb + (size_t)kid * 16384;
#pragma unroll
        for (int i = 0; i < 16; ++i) {
            int off = (tid + 256 * i) * 4;
            float4 val = *reinterpret_cast<const float4*>(src + off);
            uint2 pk;
            pk.x = pk_bf16(val.x, val.y);
            pk.y = pk_bf16(val.z, val.w);
            *reinterpret_cast<uint2*>(dst + off) = pk;
        }
        return;
    }

    // ---- V transpose: tile = V[bh][s0..s0+256][d0..d0+64] ----
    const int bh = blockIdx.z;
    const int s0 = blockIdx.x * 256;
    const int d0 = blockIdx.y * 64;

    // load f32 rows (256 B per 16 lanes), convert to bf16 on the fly
    const float* src = v + ((size_t)bh * SEQ + s0) * DH + d0;
#pragma unroll
    for (int i = 0; i < 16; ++i) {
        int id  = tid + 256 * i;
        int key = id >> 4;                  // 0..255
        int c4  = (id & 15) << 2;           // 0..60
        float4 val = *reinterpret_cast<const float4*>(src + (size_t)key * DH + c4);
        // banks: lanes 0-15 same key, d=4l -> 8B stride -> conflict-free
        unsigned short* p = &tile[key * PREP_LD + c4];
        *reinterpret_cast<unsigned int*>(p)     = pk_bf16(val.x, val.y);
        *reinterpret_cast<unsigned int*>(p + 2) = pk_bf16(val.z, val.w);
    }
    __syncthreads();

    // write VT rows: 512 B contiguous per d-row (32 lanes x 16 B)
    unsigned short* dst = vt + ((size_t)bh * DH + d0) * SEQ + s0;
#pragma unroll
    for (int i = 0; i < 8; ++i) {
        int id = tid + 256 * i;
        int dd = id >> 5;                   // 0..63
        int m  = id & 31;                   // key chunk: keys 8m..8m+7
        const unsigned short* col = &tile[(8 * m) * PREP_LD + dd];
        uint4 o;
        o.x = (unsigned)col[0 * PREP_LD] | ((unsigned)col[1 * PREP_LD] << 16);
        o.y = (unsigned)col[2 * PREP_LD] | ((unsigned)col[3 * PREP_LD] << 16);
        o.z = (unsigned)col[4 * PREP_LD] | ((unsigned)col[5 * PREP_LD] << 16);
        o.w = (unsigned)col[6 * PREP_LD] | ((unsigned)col[7 * PREP_LD] << 16);
        *reinterpret_cast<uint4*>(dst + (size_t)dd * SEQ + 8 * m) = o;
    }
}

// ---- flash attention, 32x32x16 swapped operands, dbuf single-barrier ----
// (byte-identical to round-7 verified kernel)
__global__ __launch_bounds__(256, 2) void fattn_kernel(
        const float* __restrict__ q, const unsigned short* __restrict__ kb,
        const unsigned short* __restrict__ vt, float* __restrict__ out) {
    __shared__ unsigned short Ks[2][BN * QK_LD];   // [key][d], double-buffered
    __shared__ unsigned short Vs[2][DH * VT_LD];   // [d][key], double-buffered

    // XCD swizzle: 1024 blocks = 8 XCDs x 128; 16 q-blocks per bh contiguous
    const int wid = ((blockIdx.x & 7) << 7) | (blockIdx.x >> 3);
    const int bh  = wid >> 4;
    const int q0  = (wid & 15) * BM;
    const int tid  = threadIdx.x;
    const int w    = tid >> 6;      // wave 0..3 -> q-rows [32w, 32w+32)
    const int lane = tid & 63;
    const int l31  = lane & 31;
    const int hi   = lane >> 5;

    // ---- Q (one row per lane: q0 + 32w + l31) into regs as B-frags ----
    short8 qb[8];
    {
        const float* qptr = q + ((size_t)bh * SEQ + q0 + w * 32 + l31) * DH + hi * 8;
#pragma unroll
        for (int ks = 0; ks < 8; ++ks) {
            float4 x = *reinterpret_cast<const float4*>(qptr + 16 * ks);
            float4 y = *reinterpret_cast<const float4*>(qptr + 16 * ks + 4);
            union { short8 s; uint4 u; } cv;
            cv.u.x = pk_bf16(x.x * CS, x.y * CS);
            cv.u.y = pk_bf16(x.z * CS, x.w * CS);
            cv.u.z = pk_bf16(y.x * CS, y.y * CS);
            cv.u.w = pk_bf16(y.z * CS, y.w * CS);
            qb[ks] = cv.s;
        }
    }

    f32x16 o0, o1, o2, o3;                  // O^T[d=32c+..][qrow=l31]
#pragma unroll
    for (int i = 0; i < 16; ++i) { o0[i] = 0.f; o1[i] = 0.f; o2[i] = 0.f; o3[i] = 0.f; }
    float m = -1e30f, lsum = 0.f;           // per-lane (qrow) stats; pair l<->l^32

    const unsigned short* kbp  = kb + (size_t)bh * SEQ * DH;
    const unsigned short* vptr = vt + (size_t)bh * DH * SEQ;

    // ---- T14 staging: NAMED scalars only (rule #20) ----
    uint4 kr0, kr1, kr2, kr3, vr0, vr1, vr2, vr3;
    const int krow = tid >> 4, kcol = (tid & 15) << 3;
    const int vrow = tid >> 3, vcol = (tid & 7) << 3;
    const unsigned short* kst = kbp + (size_t)krow * DH + kcol;
    const unsigned short* vst = vptr + (size_t)vrow * SEQ + vcol;

#define LOAD_TILE(K0)                                                              \
    do {                                                                           \
        const unsigned short* _kp = kst + (size_t)(K0) * DH;                       \
        kr0 = *reinterpret_cast<const uint4*>(_kp);                                \
        kr1 = *reinterpret_cast<const uint4*>(_kp + 16 * DH);                      \
        kr2 = *reinterpret_cast<const uint4*>(_kp + 32 * DH);                      \
        kr3 = *reinterpret_cast<const uint4*>(_kp + 48 * DH);                      \
        const unsigned short* _vp = vst + (K0);                                    \
        vr0 = *reinterpret_cast<const uint4*>(_vp);                                \
        vr1 = *reinterpret_cast<const uint4*>(_vp + 32 * SEQ);                     \
        vr2 = *reinterpret_cast<const uint4*>(_vp + 64 * SEQ);                     \
        vr3 = *reinterpret_cast<const uint4*>(_vp + 96 * SEQ);                     \
    } while (0)

#define WRITE_TILE(B)                                                              \
    do {                                                                           \
        *reinterpret_cast<uint4*>(&Ks[B][(krow     ) * QK_LD + kcol]) = kr0;       \
        *reinterpret_cast<uint4*>(&Ks[B][(krow + 16) * QK_LD + kcol]) = kr1;       \
        *reinterpret_cast<uint4*>(&Ks[B][(krow + 32) * QK_LD + kcol]) = kr2;       \
        *reinterpret_cast<uint4*>(&Ks[B][(krow + 48) * QK_LD + kcol]) = kr3;       \
        *reinterpret_cast<uint4*>(&Vs[B][(vrow     ) * VT_LD + vcol]) = vr0;       \
        *reinterpret_cast<uint4*>(&Vs[B][(vrow + 32) * VT_LD + vcol]) = vr1;       \
        *reinterpret_cast<uint4*>(&Vs[B][(vrow + 64) * VT_LD + vcol]) = vr2;       \
        *reinterpret_cast<uint4*>(&Vs[B][(vrow + 96) * VT_LD + vcol]) = vr3;       \
    } while (0)

    LOAD_TILE(0);
    WRITE_TILE(0);
    __syncthreads();
    int cur = 0;

    for (int kt = 0; kt < NT; ++kt) {
        // issue next tile's global loads FIRST: latency spans QK+softmax+PV
        if (kt + 1 < NT) LOAD_TILE((kt + 1) * BN);

        const unsigned short* KsA = &Ks[cur][l31 * QK_LD + hi * 8];
        const unsigned short* VsA = &Vs[cur][l31 * VT_LD + hi * 8];

        // ---- S^T = K . Q^T : s0 = keys[0,32), s1 = keys[32,64) ----
        f32x16 s0, s1;
#pragma unroll
        for (int i = 0; i < 16; ++i) { s0[i] = 0.f; s1[i] = 0.f; }
        __builtin_amdgcn_s_setprio(1);
#pragma unroll
        for (int ks = 0; ks < 8; ++ks) {
            short8 a0 = *reinterpret_cast<const short8*>(KsA + 16 * ks);
            short8 a1 = *reinterpret_cast<const short8*>(KsA + 32 * QK_LD + 16 * ks);
            s0 = __builtin_amdgcn_mfma_f32_32x32x16_bf16(a0, qb[ks], s0, 0, 0, 0);
            s1 = __builtin_amdgcn_mfma_f32_32x32x16_bf16(a1, qb[ks], s1, 0, 0, 0);
        }
        __builtin_amdgcn_s_setprio(0);

        // ---- per-lane softmax (row = own qrow; keys split lane<->lane^32) ----
        float mx = s0[0];
#pragma unroll
        for (int i = 1; i < 16; ++i) mx = fmaxf(mx, s0[i]);
#pragma unroll
        for (int i = 0; i < 16; ++i) mx = fmaxf(mx, s1[i]);
        mx = fmaxf(mx, __shfl_xor(mx, 32));     // pair-consistent row max
        if (__any(mx - m > THR)) {
            float mn = fmaxf(m, mx);
            float al = EXP2F(m - mn);
            m = mn; lsum *= al;
#pragma unroll
            for (int i = 0; i < 16; ++i) { o0[i] *= al; o1[i] *= al; o2[i] *= al; o3[i] *= al; }
        }
#pragma unroll
        for (int i = 0; i < 16; ++i) s0[i] = EXP2F(s0[i] - m);
#pragma unroll
        for (int i = 0; i < 16; ++i) s1[i] = EXP2F(s1[i] - m);
        float ls = 0.f;
#pragma unroll
        for (int i = 0; i < 16; ++i) ls += s0[i] + s1[i];
        lsum += ls;

        // ---- repack P -> PV B-frags (cvt_pk + permlane32_swap) ----
        short8 pf0 = repack_pf(s0[0], s0[1], s0[2],  s0[3],  s0[4],  s0[5],  s0[6],  s0[7],  hi);
        short8 pf1 = repack_pf(s0[8], s0[9], s0[10], s0[11], s0[12], s0[13], s0[14], s0[15], hi);
        short8 pf2 = repack_pf(s1[0], s1[1], s1[2],  s1[3],  s1[4],  s1[5],  s1[6],  s1[7],  hi);
        short8 pf3 = repack_pf(s1[8], s1[9], s1[10], s1[11], s1[12], s1[13], s1[14], s1[15], hi);

        // ---- O^T += V^T . P^T ----
        __builtin_amdgcn_s_setprio(1);
#define PV_C(OC, C)                                                                \
        {                                                                          \
            short8 va0 = *reinterpret_cast<const short8*>(VsA + (32*(C)) * VT_LD);      \
            short8 va1 = *reinterpret_cast<const short8*>(VsA + (32*(C)) * VT_LD + 16); \
            short8 va2 = *reinterpret_cast<const short8*>(VsA + (32*(C)) * VT_LD + 32); \
            short8 va3 = *reinterpret_cast<const short8*>(VsA + (32*(C)) * VT_LD + 48); \
            OC = __builtin_amdgcn_mfma_f32_32x32x16_bf16(va0, pf0, OC, 0, 0, 0);   \
            OC = __builtin_amdgcn_mfma_f32_32x32x16_bf16(va1, pf1, OC, 0, 0, 0);   \
            OC = __builtin_amdgcn_mfma_f32_32x32x16_bf16(va2, pf2, OC, 0, 0, 0);   \
            OC = __builtin_amdgcn_mfma_f32_32x32x16_bf16(va3, pf3, OC, 0, 0, 0);   \
        }
        PV_C(o0, 0) PV_C(o1, 1) PV_C(o2, 2) PV_C(o3, 3)
        __builtin_amdgcn_s_setprio(0);

        // write NEXT tile into the OTHER buffer (nobody reads it this iter),
        // then ONE barrier: publishes writes + closes reads of buf[cur]
        if (kt + 1 < NT) WRITE_TILE(cur ^ 1);
        __syncthreads();
        cur ^= 1;
    }

    // ---- epilogue: pair-reduce l, normalize, store fp32 ----
    lsum += __shfl_xor(lsum, 32);
    float inv = 1.0f / lsum;
    float* obase = out + ((size_t)bh * SEQ + q0 + w * 32 + l31) * DH + 4 * hi;
#define STORE_C(OC, C)                                                             \
    {                                                                              \
        _Pragma("unroll")                                                          \
        for (int u = 0; u < 4; ++u) {                                              \
            float4 st;                                                             \
            st.x = OC[4*u+0] * inv; st.y = OC[4*u+1] * inv;                        \
            st.z = OC[4*u+2] * inv; st.w = OC[4*u+3] * inv;                        \
            *reinterpret_cast<float4*>(obase + 32*(C) + 8*u) = st;                 \
        }                                                                          \
    }
    STORE_C(o0, 0) STORE_C(o1, 1) STORE_C(o2, 2) STORE_C(o3, 3)
}

// ---- fallback (ws < 64 MB): round-2-verified 16x16 kernel, in-loop K cvt ----
__global__ __launch_bounds__(256, 3) void fattn_fallback(
        const float* __restrict__ q, const float* __restrict__ kf,
        const unsigned short* __restrict__ vt, float* __restrict__ out) {
    __shared__ unsigned short Ks[64 * QK_LD];
    __shared__ unsigned short Vs[DH * VT_LD];
    __shared__ unsigned short Ps[64 * P_LD];

    const int wid = ((blockIdx.x & 7) << 8) | (blockIdx.x >> 3);
    const int bh  = wid >> 5;
    const int q0  = (wid & 31) * 64;
    const int tid  = threadIdx.x;
    const int w    = tid >> 6;
    const int lane = tid & 63;
    const int l15  = lane & 15;
    const int quad = lane >> 4;

    short8 qf[4];
    {
        const float* qptr = q + ((size_t)bh * SEQ + q0 + w * 16 + l15) * DH + quad * 8;
#pragma unroll
        for (int kk = 0; kk < 4; ++kk) {
            float4 x = *reinterpret_cast<const float4*>(qptr + kk * 32);
            float4 y = *reinterpret_cast<const float4*>(qptr + kk * 32 + 4);
            union { short8 s; uint4 u; } cv;
            cv.u.x = pk_bf16(x.x * CS, x.y * CS);
            cv.u.y = pk_bf16(x.z * CS, x.w * CS);
            cv.u.z = pk_bf16(y.x * CS, y.y * CS);
            cv.u.w = pk_bf16(y.z * CS, y.w * CS);
            qf[kk] = cv.s;
        }
    }

    f32x4 o[8];
#pragma unroll
    for (int t = 0; t < 8; ++t) o[t] = (f32x4){0.f, 0.f, 0.f, 0.f};
    float mrow[4] = {-1e30f, -1e30f, -1e30f, -1e30f};
    float lrow[4] = {0.f, 0.f, 0.f, 0.f};

    const float*          kfp  = kf + (size_t)bh * SEQ * DH;
    const unsigned short* vptr = vt + (size_t)bh * DH * SEQ;

    unsigned int* Ps32 = reinterpret_cast<unsigned int*>(Ps);
    const int prow_base = w * 16 + quad * 4;
    const int pdw = (l15 & 1) ? (8 + (l15 >> 1)) : (l15 >> 1);

    for (int kt = 0; kt < NT; ++kt) {
        const int k0 = kt * BN;
#pragma unroll
        for (int i = 0; i < 8; ++i) {
            int id  = tid + 256 * i;
            int row = id >> 5;
            int c4  = (id & 31) << 2;
            float4 val = *reinterpret_cast<const float4*>(kfp + (size_t)(k0 + row) * DH + c4);
            uint2 pk;
            pk.x = pk_bf16(val.x, val.y);
            pk.y = pk_bf16(val.z, val.w);
            *reinterpret_cast<uint2*>(&Ks[row * QK_LD + c4]) = pk;
        }
#pragma unroll
        for (int i = 0; i < 4; ++i) {
            int id = tid + 256 * i;
            int dd = id >> 3;
            int kc = (id & 7) << 3;
            *reinterpret_cast<uint4*>(&Vs[dd * VT_LD + kc]) =
                *reinterpret_cast<const uint4*>(vptr + (size_t)dd * SEQ + k0 + kc);
        }
        __syncthreads();

        f32x4 acc[4];
#pragma unroll
        for (int t = 0; t < 4; ++t) acc[t] = (f32x4){0.f, 0.f, 0.f, 0.f};
#pragma unroll
        for (int kk = 0; kk < 4; ++kk) {
            const int koff = kk * 32 + quad * 8;
#pragma unroll
            for (int t = 0; t < 4; ++t) {
                short8 b = *reinterpret_cast<const short8*>(&Ks[(t * 16 + l15) * QK_LD + koff]);
                acc[t] = __builtin_amdgcn_mfma_f32_16x16x32_bf16(qf[kk], b, acc[t], 0, 0, 0);
            }
        }

        float lm[4];
#pragma unroll
        for (int r = 0; r < 4; ++r)
            lm[r] = fmaxf(fmaxf(acc[0][r], acc[1][r]), fmaxf(acc[2][r], acc[3][r]));
        float need = fmaxf(fmaxf(lm[0] - mrow[0], lm[1] - mrow[1]),
                           fmaxf(lm[2] - mrow[2], lm[3] - mrow[3]));
        if (__any(need > THR)) {
#pragma unroll
            for (int r = 0; r < 4; ++r) {
                float mx = lm[r];
#pragma unroll
                for (int off = 1; off < 16; off <<= 1)
                    mx = fmaxf(mx, __shfl_xor(mx, off));
                float mnew  = fmaxf(mrow[r], mx);
                float alpha = EXP2F(mrow[r] - mnew);
                mrow[r] = mnew;
                lrow[r] *= alpha;
#pragma unroll
                for (int t = 0; t < 8; ++t) o[t][r] *= alpha;
            }
        }

#pragma unroll
        for (int r = 0; r < 4; ++r) {
            float p0 = EXP2F(acc[0][r] - mrow[r]);
            float p1 = EXP2F(acc[1][r] - mrow[r]);
            float p2 = EXP2F(acc[2][r] - mrow[r]);
            float p3 = EXP2F(acc[3][r] - mrow[r]);
            lrow[r] += (p0 + p1) + (p2 + p3);
            unsigned int a01 = pk_bf16(p0, p1);
            unsigned int a23 = pk_bf16(p2, p3);
            unsigned int s01 = __shfl_xor((int)a01, 1);
            unsigned int s23 = __shfl_xor((int)a23, 1);
            unsigned int w0, w1;
            if (l15 & 1) {
                w0 = (s01 >> 16) | (a01 & 0xffff0000u);
                w1 = (s23 >> 16) | (a23 & 0xffff0000u);
            } else {
                w0 = (a01 & 0xffffu) | (s01 << 16);
                w1 = (a23 & 0xffffu) | (s23 << 16);
            }
            const int dw = (prow_base + r) * (P_LD / 2) + pdw;
            Ps32[dw]      = w0;
            Ps32[dw + 16] = w1;
        }

#pragma unroll
        for (int kk = 0; kk < 2; ++kk) {
            const int koff = kk * 32 + quad * 8;
            short8 a = *reinterpret_cast<const short8*>(&Ps[(w * 16 + l15) * P_LD + koff]);
#pragma unroll
            for (int t = 0; t < 8; ++t) {
                short8 b = *reinterpret_cast<const short8*>(&Vs[(t * 16 + l15) * VT_LD + koff]);
                o[t] = __builtin_amdgcn_mfma_f32_16x16x32_bf16(a, b, o[t], 0, 0, 0);
            }
        }
        __syncthreads();
    }

#pragma unroll
    for (int r = 0; r < 4; ++r) {
#pragma unroll
        for (int off = 1; off < 16; off <<= 1)
            lrow[r] += __shfl_xor(lrow[r], off);
    }
    float* obase = out + ((size_t)bh * SEQ + q0) * DH;
#pragma unroll
    for (int r = 0; r < 4; ++r) {
        float inv = 1.0f / lrow[r];
        int row = w * 16 + quad * 4 + r;
#pragma unroll
        for (int t = 0; t < 8; ++t)
            obase[(size_t)row * DH + t * 16 + l15] = o[t][r] * inv;
    }
}

extern "C" void kernel_launch(void* const* d_in, const int* in_sizes, int n_in,
                              void* d_out, int out_size, void* d_ws, size_t ws_size,
                              hipStream_t stream) {
    const float* q = (const float*)d_in[0];
    const float* k = (const float*)d_in[1];
    const float* v = (const float*)d_in[2];
    float* out = (float*)d_out;
    unsigned short* vt = (unsigned short*)d_ws;                   // 32 MB

    const size_t vt_elems = (size_t)NBH * SEQ * DH;               // 16M shorts
    if (ws_size >= 2 * vt_elems * sizeof(unsigned short)) {
        unsigned short* kbuf = vt + vt_elems;
        prep_kernel<true><<<dim3(16, 2, NBH), dim3(256), 0, stream>>>(v, vt, k, kbuf);
        fattn_kernel<<<dim3((SEQ / BM) * NBH), dim3(256), 0, stream>>>(q, kbuf, vt, out);
    } else {
        prep_kernel<false><<<dim3(16, 2, NBH), dim3(256), 0, stream>>>(v, vt, nullptr, nullptr);
        fattn_fallback<<<dim3((SEQ / 64) * NBH), dim3(256), 0, stream>>>(q, k, vt, out);
    }
}

// Round 9
// 358.437 us; speedup vs baseline: 1.0138x; 1.0138x over previous
//
#include <hip/hip_runtime.h>
#include <hip/hip_bf16.h>

// Attention fwd: B=4 H=16 S=2048 D=128, fp32 in/out, scale = 128^-0.5.
// Prep: one kernel, grid (16,2,64):
//   x<8 : V-transpose 256-key x 64-d tiles -> VT[bh][d][s] bf16.
//         REGISTER transpose: lanes 0-31 load float2 of key k, lanes 32-63 of
//         key k+1 (same d); permlane32_swap gives every lane both keys at its
//         d; cvt_pk packs u32 = {bf16[k], bf16[k+1]} = one VT-row element.
//         LDS: u32 writes (4-way worst) + b64 row reads -> NO scalar columns
//         (r5-r8 preps were all scalar-column-read bound; gap stuck ~150us).
//   x>=8: K f32 -> bf16 streaming convert (1024 blocks, float4->uint2).
// fattn: UNCHANGED from round-7 verified kernel (189us, MfmaUtil 33%).

#define SEQ 2048
#define DH  128
#define NBH 64          // B*H
#define BM  128         // Q rows per block (32 per wave)
#define BN  64          // keys per KV iteration
#define NT  (SEQ / BN)  // 32 KV tiles
#define QK_LD 136       // bf16 elems per row for K tile (128+8): 272B rows
#define VT_LD 72        // (64+8): 144B rows
#define P_LD  72        // fallback kernel only
#define TP_LD 130       // prep tileT row pitch in u32 (even -> b64-aligned)
#define THR 8.0f        // defer-max threshold (exp2 domain): P <= 2^8

typedef __attribute__((ext_vector_type(8))) short short8;
typedef __attribute__((ext_vector_type(4))) float f32x4;
typedef __attribute__((ext_vector_type(16))) float f32x16;
typedef __attribute__((ext_vector_type(2))) unsigned int u32x2;

#if __has_builtin(__builtin_amdgcn_exp2f)
#define EXP2F(x) __builtin_amdgcn_exp2f(x)
#else
#define EXP2F(x) exp2f(x)
#endif

// softmax scale folded with log2(e), pre-applied to Q at load time
#define CS (0.08838834764831845f * 1.44269504088896340736f)

__device__ __forceinline__ unsigned int pk_bf16(float lo, float hi) {
    union { __hip_bfloat162 h; unsigned int u; } cv;
    cv.h = __float22bfloat162_rn(make_float2(lo, hi));   // v_cvt_pk_bf16_f32
    return cv.u;
}

// Build one PV B-frag (16 keys) from 8 fp32 P values held across the lane^32
// pair. permlane32_swap exchanges the complementary dwords.
__device__ __forceinline__ short8 repack_pf(float a0, float a1, float a2, float a3,
                                            float a4, float a5, float a6, float a7,
                                            int hi) {
    unsigned pq0 = pk_bf16(a0, a1);
    unsigned pq1 = pk_bf16(a2, a3);
    unsigned pq2 = pk_bf16(a4, a5);
    unsigned pq3 = pk_bf16(a6, a7);
    union { short8 s; uint4 u; } cv;
#if __has_builtin(__builtin_amdgcn_permlane32_swap)
    u32x2 r02 = __builtin_amdgcn_permlane32_swap(pq0, pq2, false, false);
    u32x2 r13 = __builtin_amdgcn_permlane32_swap(pq1, pq3, false, false);
    cv.u.x = r02[0]; cv.u.y = r13[0]; cv.u.z = r02[1]; cv.u.w = r13[1];
    (void)hi;
#else
    unsigned px0 = (unsigned)__shfl_xor((int)pq0, 32);
    unsigned px1 = (unsigned)__shfl_xor((int)pq1, 32);
    unsigned px2 = (unsigned)__shfl_xor((int)pq2, 32);
    unsigned px3 = (unsigned)__shfl_xor((int)pq3, 32);
    cv.u.x = hi ? px2 : pq0;
    cv.u.y = hi ? px3 : pq1;
    cv.u.z = hi ? pq2 : px0;
    cv.u.w = hi ? pq3 : px1;
#endif
    return cv.s;
}

// ---- prep: x<8 -> V transpose (256-key x 64-d tile); x>=8 -> K convert ----
template<bool DOK>
__global__ __launch_bounds__(256) void prep_kernel(
        const float* __restrict__ v, unsigned short* __restrict__ vt,
        const float* __restrict__ k, unsigned short* __restrict__ kb) {
    __shared__ unsigned int tileT[64 * TP_LD];   // u32 = 2 keys bf16; 33,280 B
    const int tid = threadIdx.x;

    if (blockIdx.x >= 8) {
        // ---- K convert: 1024 blocks x 16384 floats, pure streaming ----
        if (!DOK) return;
        const int kid = (blockIdx.x - 8) + 8 * blockIdx.y + 16 * blockIdx.z;
        const float* src = k + (size_t)kid * 16384;
        unsigned short* dst = kb + (size_t)kid * 16384;
#pragma unroll
        for (int i = 0; i < 16; ++i) {
            int off = (tid + 256 * i) * 4;
            float4 val = *reinterpret_cast<const float4*>(src + off);
            uint2 pk;
            pk.x = pk_bf16(val.x, val.y);
            pk.y = pk_bf16(val.z, val.w);
            *reinterpret_cast<uint2*>(dst + off) = pk;
        }
        return;
    }

    // ---- V transpose: tile = V[bh][s0..s0+256][d0..d0+64] ----
    const int bh = blockIdx.z;
    const int s0 = blockIdx.x * 256;
    const int d0 = blockIdx.y * 64;
    const int lane = tid & 63;
    const int wv   = tid >> 6;          // wave 0..3 -> keypairs [32wv, 32wv+32)
    const int l31  = lane & 31;
    const int hiv  = lane >> 5;

    // load: lanes 0-31 key 2kp (256B row-chunk), lanes 32-63 key 2kp+1;
    // permlane32_swap(x,x) -> every lane holds BOTH keys' value at its d.
    const float* srcv = v + ((size_t)bh * SEQ + s0) * DH + d0 + 2 * l31;
    const int drow = 2 * l31 + hiv;     // row this lane writes (lo: even, hi: odd)
#pragma unroll 4
    for (int i = 0; i < 32; ++i) {
        const int kp = wv * 32 + i;     // keypair 0..127
        float2 X = *reinterpret_cast<const float2*>(srcv + (size_t)(2 * kp + hiv) * DH);
        union { float f; unsigned u; } bx, by;
        bx.f = X.x; by.f = X.y;
        float k0d0, k1d0, k0d1, k1d1;
#if __has_builtin(__builtin_amdgcn_permlane32_swap)
        u32x2 rx = __builtin_amdgcn_permlane32_swap(bx.u, bx.u, false, false);
        u32x2 ry = __builtin_amdgcn_permlane32_swap(by.u, by.u, false, false);
        union { unsigned u; float f; } c0, c1, c2, c3;
        c0.u = rx[0]; c1.u = rx[1]; c2.u = ry[0]; c3.u = ry[1];
        k0d0 = c0.f; k1d0 = c1.f; k0d1 = c2.f; k1d1 = c3.f;
#else
        float xo = __shfl_xor(X.x, 32), yo = __shfl_xor(X.y, 32);
        k0d0 = hiv ? xo : X.x;  k1d0 = hiv ? X.x : xo;
        k0d1 = hiv ? yo : X.y;  k1d1 = hiv ? X.y : yo;
#endif
        // lo lane owns row d (X.x slot), hi lane owns row d+1 (X.y slot)
        unsigned pk = hiv ? pk_bf16(k0d1, k1d1) : pk_bf16(k0d0, k1d0);
        tileT[drow * TP_LD + kp] = pk;  // banks (2*drow+kp)%32: 4-way worst
    }
    __syncthreads();

    // store: row dd = 256 keys = 128 u32 = 512B contiguous (2x b64 LDS reads)
    unsigned short* dst = vt + ((size_t)bh * DH + d0) * SEQ + s0;
#pragma unroll
    for (int i = 0; i < 8; ++i) {
        int id = tid + 256 * i;
        int dd = id >> 5;               // 0..63
        int m  = id & 31;               // keys 8m..8m+7 (4 u32)
        const unsigned int* p = &tileT[dd * TP_LD + 4 * m];
        uint2 a = *reinterpret_cast<const uint2*>(p);       // 8B-aligned (even pitch)
        uint2 b = *reinterpret_cast<const uint2*>(p + 2);
        uint4 o; o.x = a.x; o.y = a.y; o.z = b.x; o.w = b.y;
        *reinterpret_cast<uint4*>(dst + (size_t)dd * SEQ + 8 * m) = o;
    }
}

// ---- flash attention, 32x32x16 swapped operands, dbuf single-barrier ----
// (byte-identical to round-7 verified kernel)
__global__ __launch_bounds__(256, 2) void fattn_kernel(
        const float* __restrict__ q, const unsigned short* __restrict__ kb,
        const unsigned short* __restrict__ vt, float* __restrict__ out) {
    __shared__ unsigned short Ks[2][BN * QK_LD];   // [key][d], double-buffered
    __shared__ unsigned short Vs[2][DH * VT_LD];   // [d][key], double-buffered

    // XCD swizzle: 1024 blocks = 8 XCDs x 128; 16 q-blocks per bh contiguous
    const int wid = ((blockIdx.x & 7) << 7) | (blockIdx.x >> 3);
    const int bh  = wid >> 4;
    const int q0  = (wid & 15) * BM;
    const int tid  = threadIdx.x;
    const int w    = tid >> 6;      // wave 0..3 -> q-rows [32w, 32w+32)
    const int lane = tid & 63;
    const int l31  = lane & 31;
    const int hi   = lane >> 5;

    // ---- Q (one row per lane: q0 + 32w + l31) into regs as B-frags ----
    short8 qb[8];
    {
        const float* qptr = q + ((size_t)bh * SEQ + q0 + w * 32 + l31) * DH + hi * 8;
#pragma unroll
        for (int ks = 0; ks < 8; ++ks) {
            float4 x = *reinterpret_cast<const float4*>(qptr + 16 * ks);
            float4 y = *reinterpret_cast<const float4*>(qptr + 16 * ks + 4);
            union { short8 s; uint4 u; } cv;
            cv.u.x = pk_bf16(x.x * CS, x.y * CS);
            cv.u.y = pk_bf16(x.z * CS, x.w * CS);
            cv.u.z = pk_bf16(y.x * CS, y.y * CS);
            cv.u.w = pk_bf16(y.z * CS, y.w * CS);
            qb[ks] = cv.s;
        }
    }

    f32x16 o0, o1, o2, o3;                  // O^T[d=32c+..][qrow=l31]
#pragma unroll
    for (int i = 0; i < 16; ++i) { o0[i] = 0.f; o1[i] = 0.f; o2[i] = 0.f; o3[i] = 0.f; }
    float m = -1e30f, lsum = 0.f;           // per-lane (qrow) stats; pair l<->l^32

    const unsigned short* kbp  = kb + (size_t)bh * SEQ * DH;
    const unsigned short* vptr = vt + (size_t)bh * DH * SEQ;

    // ---- T14 staging: NAMED scalars only (rule #20) ----
    uint4 kr0, kr1, kr2, kr3, vr0, vr1, vr2, vr3;
    const int krow = tid >> 4, kcol = (tid & 15) << 3;
    const int vrow = tid >> 3, vcol = (tid & 7) << 3;
    const unsigned short* kst = kbp + (size_t)krow * DH + kcol;
    const unsigned short* vst = vptr + (size_t)vrow * SEQ + vcol;

#define LOAD_TILE(K0)                                                              \
    do {                                                                           \
        const unsigned short* _kp = kst + (size_t)(K0) * DH;                       \
        kr0 = *reinterpret_cast<const uint4*>(_kp);                                \
        kr1 = *reinterpret_cast<const uint4*>(_kp + 16 * DH);                      \
        kr2 = *reinterpret_cast<const uint4*>(_kp + 32 * DH);                      \
        kr3 = *reinterpret_cast<const uint4*>(_kp + 48 * DH);                      \
        const unsigned short* _vp = vst + (K0);                                    \
        vr0 = *reinterpret_cast<const uint4*>(_vp);                                \
        vr1 = *reinterpret_cast<const uint4*>(_vp + 32 * SEQ);                     \
        vr2 = *reinterpret_cast<const uint4*>(_vp + 64 * SEQ);                     \
        vr3 = *reinterpret_cast<const uint4*>(_vp + 96 * SEQ);                     \
    } while (0)

#define WRITE_TILE(B)                                                              \
    do {                                                                           \
        *reinterpret_cast<uint4*>(&Ks[B][(krow     ) * QK_LD + kcol]) = kr0;       \
        *reinterpret_cast<uint4*>(&Ks[B][(krow + 16) * QK_LD + kcol]) = kr1;       \
        *reinterpret_cast<uint4*>(&Ks[B][(krow + 32) * QK_LD + kcol]) = kr2;       \
        *reinterpret_cast<uint4*>(&Ks[B][(krow + 48) * QK_LD + kcol]) = kr3;       \
        *reinterpret_cast<uint4*>(&Vs[B][(vrow     ) * VT_LD + vcol]) = vr0;       \
        *reinterpret_cast<uint4*>(&Vs[B][(vrow + 32) * VT_LD + vcol]) = vr1;       \
        *reinterpret_cast<uint4*>(&Vs[B][(vrow + 64) * VT_LD + vcol]) = vr2;       \
        *reinterpret_cast<uint4*>(&Vs[B][(vrow + 96) * VT_LD + vcol]) = vr3;       \
    } while (0)

    LOAD_TILE(0);
    WRITE_TILE(0);
    __syncthreads();
    int cur = 0;

    for (int kt = 0; kt < NT; ++kt) {
        // issue next tile's global loads FIRST: latency spans QK+softmax+PV
        if (kt + 1 < NT) LOAD_TILE((kt + 1) * BN);

        const unsigned short* KsA = &Ks[cur][l31 * QK_LD + hi * 8];
        const unsigned short* VsA = &Vs[cur][l31 * VT_LD + hi * 8];

        // ---- S^T = K . Q^T : s0 = keys[0,32), s1 = keys[32,64) ----
        f32x16 s0, s1;
#pragma unroll
        for (int i = 0; i < 16; ++i) { s0[i] = 0.f; s1[i] = 0.f; }
        __builtin_amdgcn_s_setprio(1);
#pragma unroll
        for (int ks = 0; ks < 8; ++ks) {
            short8 a0 = *reinterpret_cast<const short8*>(KsA + 16 * ks);
            short8 a1 = *reinterpret_cast<const short8*>(KsA + 32 * QK_LD + 16 * ks);
            s0 = __builtin_amdgcn_mfma_f32_32x32x16_bf16(a0, qb[ks], s0, 0, 0, 0);
            s1 = __builtin_amdgcn_mfma_f32_32x32x16_bf16(a1, qb[ks], s1, 0, 0, 0);
        }
        __builtin_amdgcn_s_setprio(0);

        // ---- per-lane softmax (row = own qrow; keys split lane<->lane^32) ----
        float mx = s0[0];
#pragma unroll
        for (int i = 1; i < 16; ++i) mx = fmaxf(mx, s0[i]);
#pragma unroll
        for (int i = 0; i < 16; ++i) mx = fmaxf(mx, s1[i]);
        mx = fmaxf(mx, __shfl_xor(mx, 32));     // pair-consistent row max
        if (__any(mx - m > THR)) {
            float mn = fmaxf(m, mx);
            float al = EXP2F(m - mn);
            m = mn; lsum *= al;
#pragma unroll
            for (int i = 0; i < 16; ++i) { o0[i] *= al; o1[i] *= al; o2[i] *= al; o3[i] *= al; }
        }
#pragma unroll
        for (int i = 0; i < 16; ++i) s0[i] = EXP2F(s0[i] - m);
#pragma unroll
        for (int i = 0; i < 16; ++i) s1[i] = EXP2F(s1[i] - m);
        float ls = 0.f;
#pragma unroll
        for (int i = 0; i < 16; ++i) ls += s0[i] + s1[i];
        lsum += ls;

        // ---- repack P -> PV B-frags (cvt_pk + permlane32_swap) ----
        short8 pf0 = repack_pf(s0[0], s0[1], s0[2],  s0[3],  s0[4],  s0[5],  s0[6],  s0[7],  hi);
        short8 pf1 = repack_pf(s0[8], s0[9], s0[10], s0[11], s0[12], s0[13], s0[14], s0[15], hi);
        short8 pf2 = repack_pf(s1[0], s1[1], s1[2],  s1[3],  s1[4],  s1[5],  s1[6],  s1[7],  hi);
        short8 pf3 = repack_pf(s1[8], s1[9], s1[10], s1[11], s1[12], s1[13], s1[14], s1[15], hi);

        // ---- O^T += V^T . P^T ----
        __builtin_amdgcn_s_setprio(1);
#define PV_C(OC, C)                                                                \
        {                                                                          \
            short8 va0 = *reinterpret_cast<const short8*>(VsA + (32*(C)) * VT_LD);      \
            short8 va1 = *reinterpret_cast<const short8*>(VsA + (32*(C)) * VT_LD + 16); \
            short8 va2 = *reinterpret_cast<const short8*>(VsA + (32*(C)) * VT_LD + 32); \
            short8 va3 = *reinterpret_cast<const short8*>(VsA + (32*(C)) * VT_LD + 48); \
            OC = __builtin_amdgcn_mfma_f32_32x32x16_bf16(va0, pf0, OC, 0, 0, 0);   \
            OC = __builtin_amdgcn_mfma_f32_32x32x16_bf16(va1, pf1, OC, 0, 0, 0);   \
            OC = __builtin_amdgcn_mfma_f32_32x32x16_bf16(va2, pf2, OC, 0, 0, 0);   \
            OC = __builtin_amdgcn_mfma_f32_32x32x16_bf16(va3, pf3, OC, 0, 0, 0);   \
        }
        PV_C(o0, 0) PV_C(o1, 1) PV_C(o2, 2) PV_C(o3, 3)
        __builtin_amdgcn_s_setprio(0);

        // write NEXT tile into the OTHER buffer (nobody reads it this iter),
        // then ONE barrier: publishes writes + closes reads of buf[cur]
        if (kt + 1 < NT) WRITE_TILE(cur ^ 1);
        __syncthreads();
        cur ^= 1;
    }

    // ---- epilogue: pair-reduce l, normalize, store fp32 ----
    lsum += __shfl_xor(lsum, 32);
    float inv = 1.0f / lsum;
    float* obase = out + ((size_t)bh * SEQ + q0 + w * 32 + l31) * DH + 4 * hi;
#define STORE_C(OC, C)                                                             \
    {                                                                              \
        _Pragma("unroll")                                                          \
        for (int u = 0; u < 4; ++u) {                                              \
            float4 st;                                                             \
            st.x = OC[4*u+0] * inv; st.y = OC[4*u+1] * inv;                        \
            st.z = OC[4*u+2] * inv; st.w = OC[4*u+3] * inv;                        \
            *reinterpret_cast<float4*>(obase + 32*(C) + 8*u) = st;                 \
        }                                                                          \
    }
    STORE_C(o0, 0) STORE_C(o1, 1) STORE_C(o2, 2) STORE_C(o3, 3)
}

// ---- fallback (ws < 64 MB): round-2-verified 16x16 kernel, in-loop K cvt ----
__global__ __launch_bounds__(256, 3) void fattn_fallback(
        const float* __restrict__ q, const float* __restrict__ kf,
        const unsigned short* __restrict__ vt, float* __restrict__ out) {
    __shared__ unsigned short Ks[64 * QK_LD];
    __shared__ unsigned short Vs[DH * VT_LD];
    __shared__ unsigned short Ps[64 * P_LD];

    const int wid = ((blockIdx.x & 7) << 8) | (blockIdx.x >> 3);
    const int bh  = wid >> 5;
    const int q0  = (wid & 31) * 64;
    const int tid  = threadIdx.x;
    const int w    = tid >> 6;
    const int lane = tid & 63;
    const int l15  = lane & 15;
    const int quad = lane >> 4;

    short8 qf[4];
    {
        const float* qptr = q + ((size_t)bh * SEQ + q0 + w * 16 + l15) * DH + quad * 8;
#pragma unroll
        for (int kk = 0; kk < 4; ++kk) {
            float4 x = *reinterpret_cast<const float4*>(qptr + kk * 32);
            float4 y = *reinterpret_cast<const float4*>(qptr + kk * 32 + 4);
            union { short8 s; uint4 u; } cv;
            cv.u.x = pk_bf16(x.x * CS, x.y * CS);
            cv.u.y = pk_bf16(x.z * CS, x.w * CS);
            cv.u.z = pk_bf16(y.x * CS, y.y * CS);
            cv.u.w = pk_bf16(y.z * CS, y.w * CS);
            qf[kk] = cv.s;
        }
    }

    f32x4 o[8];
#pragma unroll
    for (int t = 0; t < 8; ++t) o[t] = (f32x4){0.f, 0.f, 0.f, 0.f};
    float mrow[4] = {-1e30f, -1e30f, -1e30f, -1e30f};
    float lrow[4] = {0.f, 0.f, 0.f, 0.f};

    const float*          kfp  = kf + (size_t)bh * SEQ * DH;
    const unsigned short* vptr = vt + (size_t)bh * DH * SEQ;

    unsigned int* Ps32 = reinterpret_cast<unsigned int*>(Ps);
    const int prow_base = w * 16 + quad * 4;
    const int pdw = (l15 & 1) ? (8 + (l15 >> 1)) : (l15 >> 1);

    for (int kt = 0; kt < NT; ++kt) {
        const int k0 = kt * BN;
#pragma unroll
        for (int i = 0; i < 8; ++i) {
            int id  = tid + 256 * i;
            int row = id >> 5;
            int c4  = (id & 31) << 2;
            float4 val = *reinterpret_cast<const float4*>(kfp + (size_t)(k0 + row) * DH + c4);
            uint2 pk;
            pk.x = pk_bf16(val.x, val.y);
            pk.y = pk_bf16(val.z, val.w);
            *reinterpret_cast<uint2*>(&Ks[row * QK_LD + c4]) = pk;
        }
#pragma unroll
        for (int i = 0; i < 4; ++i) {
            int id = tid + 256 * i;
            int dd = id >> 3;
            int kc = (id & 7) << 3;
            *reinterpret_cast<uint4*>(&Vs[dd * VT_LD + kc]) =
                *reinterpret_cast<const uint4*>(vptr + (size_t)dd * SEQ + k0 + kc);
        }
        __syncthreads();

        f32x4 acc[4];
#pragma unroll
        for (int t = 0; t < 4; ++t) acc[t] = (f32x4){0.f, 0.f, 0.f, 0.f};
#pragma unroll
        for (int kk = 0; kk < 4; ++kk) {
            const int koff = kk * 32 + quad * 8;
#pragma unroll
            for (int t = 0; t < 4; ++t) {
                short8 b = *reinterpret_cast<const short8*>(&Ks[(t * 16 + l15) * QK_LD + koff]);
                acc[t] = __builtin_amdgcn_mfma_f32_16x16x32_bf16(qf[kk], b, acc[t], 0, 0, 0);
            }
        }

        float lm[4];
#pragma unroll
        for (int r = 0; r < 4; ++r)
            lm[r] = fmaxf(fmaxf(acc[0][r], acc[1][r]), fmaxf(acc[2][r], acc[3][r]));
        float need = fmaxf(fmaxf(lm[0] - mrow[0], lm[1] - mrow[1]),
                           fmaxf(lm[2] - mrow[2], lm[3] - mrow[3]));
        if (__any(need > THR)) {
#pragma unroll
            for (int r = 0; r < 4; ++r) {
                float mx = lm[r];
#pragma unroll
                for (int off = 1; off < 16; off <<= 1)
                    mx = fmaxf(mx, __shfl_xor(mx, off));
                float mnew  = fmaxf(mrow[r], mx);
                float alpha = EXP2F(mrow[r] - mnew);
                mrow[r] = mnew;
                lrow[r] *= alpha;
#pragma unroll
                for (int t = 0; t < 8; ++t) o[t][r] *= alpha;
            }
        }

#pragma unroll
        for (int r = 0; r < 4; ++r) {
            float p0 = EXP2F(acc[0][r] - mrow[r]);
            float p1 = EXP2F(acc[1][r] - mrow[r]);
            float p2 = EXP2F(acc[2][r] - mrow[r]);
            float p3 = EXP2F(acc[3][r] - mrow[r]);
            lrow[r] += (p0 + p1) + (p2 + p3);
            unsigned int a01 = pk_bf16(p0, p1);
            unsigned int a23 = pk_bf16(p2, p3);
            unsigned int s01 = __shfl_xor((int)a01, 1);
            unsigned int s23 = __shfl_xor((int)a23, 1);
            unsigned int w0, w1;
            if (l15 & 1) {
                w0 = (s01 >> 16) | (a01 & 0xffff0000u);
                w1 = (s23 >> 16) | (a23 & 0xffff0000u);
            } else {
                w0 = (a01 & 0xffffu) | (s01 << 16);
                w1 = (a23 & 0xffffu) | (s23 << 16);
            }
            const int dw = (prow_base + r) * (P_LD / 2) + pdw;
            Ps32[dw]      = w0;
            Ps32[dw + 16] = w1;
        }

#pragma unroll
        for (int kk = 0; kk < 2; ++kk) {
            const int koff = kk * 32 + quad * 8;
            short8 a = *reinterpret_cast<const short8*>(&Ps[(w * 16 + l15) * P_LD + koff]);
#pragma unroll
            for (int t = 0; t < 8; ++t) {
                short8 b = *reinterpret_cast<const short8*>(&Vs[(t * 16 + l15) * VT_LD + koff]);
                o[t] = __builtin_amdgcn_mfma_f32_16x16x32_bf16(a, b, o[t], 0, 0, 0);
            }
        }
        __syncthreads();
    }

#pragma unroll
    for (int r = 0; r < 4; ++r) {
#pragma unroll
        for (int off = 1; off < 16; off <<= 1)
            lrow[r] += __shfl_xor(lrow[r], off);
    }
    float* obase = out + ((size_t)bh * SEQ + q0) * DH;
#pragma unroll
    for (int r = 0; r < 4; ++r) {
        float inv = 1.0f / lrow[r];
        int row = w * 16 + quad * 4 + r;
#pragma unroll
        for (int t = 0; t < 8; ++t)
            obase[(size_t)row * DH + t * 16 + l15] = o[t][r] * inv;
    }
}

extern "C" void kernel_launch(void* const* d_in, const int* in_sizes, int n_in,
                              void* d_out, int out_size, void* d_ws, size_t ws_size,
                              hipStream_t stream) {
    const float* q = (const float*)d_in[0];
    const float* k = (const float*)d_in[1];
    const float* v = (const float*)d_in[2];
    float* out = (float*)d_out;
    unsigned short* vt = (unsigned short*)d_ws;                   // 32 MB

    const size_t vt_elems = (size_t)NBH * SEQ * DH;               // 16M shorts
    if (ws_size >= 2 * vt_elems * sizeof(unsigned short)) {
        unsigned short* kbuf = vt + vt_elems;
        prep_kernel<true><<<dim3(16, 2, NBH), dim3(256), 0, stream>>>(v, vt, k, kbuf);
        fattn_kernel<<<dim3((SEQ / BM) * NBH), dim3(256), 0, stream>>>(q, kbuf, vt, out);
    } else {
        prep_kernel<false><<<dim3(16, 2, NBH), dim3(256), 0, stream>>>(v, vt, nullptr, nullptr);
        fattn_fallback<<<dim3((SEQ / 64) * NBH), dim3(256), 0, stream>>>(q, k, vt, out);
    }
}